// Round 17
// baseline (209.147 us; speedup 1.0000x reference)
//
#include <hip/hip_runtime.h>
#include <math.h>

#define NB 32
#define NN 512
#define ROWC 2048ull

typedef __attribute__((ext_vector_type(8))) short bf16x8;
typedef __attribute__((ext_vector_type(4))) float f32x4;

__device__ __forceinline__ unsigned int fbits(float f) {
  union { float f; unsigned int u; } v; v.f = f; return v.u;
}
__device__ __forceinline__ float bcast(unsigned int u) {
  union { unsigned int u; float f; } v; v.u = u; return v.f;
}
// round-to-nearest-even bf16, returned in low 16 bits
__device__ __forceinline__ unsigned int bf16_rne(float f) {
  unsigned int b = fbits(f);
  return (b + 0x7FFFu + ((b >> 16) & 1u)) >> 16;
}

// async global->LDS, 16B per lane; LDS dest = wave-uniform base + lane*16.
__device__ __forceinline__ void gload16(const uint4* g, uint4* l) {
  __builtin_amdgcn_global_load_lds(
      (const __attribute__((address_space(1))) void*)g,
      (__attribute__((address_space(3))) void*)l, 16, 0, 0);
}

// Fragment-ordered LDS address (BK=64 form) used by gemm_wp / gemm_wh.
__device__ __forceinline__ int frag_byte(int blk, int lane, int khalf) {
  int base = ((((khalf << 3) + blk) << 6) + lane) << 4;
  int swz = (blk ^ (lane >> 4) ^ (khalf << 2)) & 7;
  return base ^ (swz << 4);
}

// --- Kernel 0: fp32 -> hi/lo bf16, PRE-TILED in MFMA fragment order --------
__global__ __launch_bounds__(256) void convert_tiled(
    const float* __restrict__ px, const float* __restrict__ hx,
    uint4* __restrict__ pxh, uint4* __restrict__ pxl,
    uint4* __restrict__ hxh, uint4* __restrict__ hxl) {
  const int bp = blockIdx.x;            // b*4 + P, 0..127
  const float* src = (blockIdx.y ? hx : px) + (size_t)bp * 128 * NN;
  uint4* dh = (blockIdx.y ? hxh : pxh) + (size_t)bp * 16 * 512;
  uint4* dl = (blockIdx.y ? hxl : pxl) + (size_t)bp * 16 * 512;
  const int t = threadIdx.x;
#pragma unroll
  for (int i = 0; i < 8; ++i) {
    int idx = i * 256 + t;              // 0..2047 = (ks, row)
    int ks = idx >> 7, row = idx & 127;
    const float* rp = src + (size_t)row * NN + ks * 32;
    int ub = ks * 512 + (row >> 4) * 64 + (row & 15);
#pragma unroll
    for (int ko = 0; ko < 4; ++ko) {
      float4 f0 = *(const float4*)(rp + ko * 8);
      float4 f1 = *(const float4*)(rp + ko * 8 + 4);
      float ff[8] = {f0.x, f0.y, f0.z, f0.w, f1.x, f1.y, f1.z, f1.w};
      union { unsigned short us[8]; uint4 u4; } hi, lo;
#pragma unroll
      for (int q = 0; q < 8; ++q) {
        unsigned int bq = fbits(ff[q]);
        hi.us[q] = (unsigned short)(bq >> 16);
        float r = ff[q] - bcast(bq & 0xFFFF0000u);
        lo.us[q] = (unsigned short)(fbits(r) >> 16);
      }
      dh[ub + 16 * ko] = hi.u4;
      dl[ub + 16 * ko] = lo.u4;
    }
  }
}

// --- Kernel 1: e = px.hx^T (3-term split) + fused masked row/col stats -----
// r14/r16 dataflow, but staging via global_load_lds width=16 (m193: +67% on
// this exact 2-barrier structure): no VGPR round-trip, no ds_write insts.
// Pre-tiled linear layout is exactly the wave-uniform-base + lane*16 pattern
// the instruction requires.
__global__ __launch_bounds__(256) void gemm_e_stats(
    const uint4* __restrict__ Ahg, const uint4* __restrict__ Alg,
    const uint4* __restrict__ Bhg, const uint4* __restrict__ Blg,
    const int* __restrict__ p_mask, const int* __restrict__ h_mask,
    float* __restrict__ e,
    float* __restrict__ rpm, float* __restrict__ rps,
    float* __restrict__ cpm, float* __restrict__ cps) {
  __shared__ union {
    struct { uint4 Ah[512]; uint4 Al[512]; uint4 Bh[512]; uint4 Bl[512]; } s;
    float ep[64][132];
  } u;
  __shared__ int pmk[128], hmk[128];
  __shared__ float st_m[2][128], st_s[2][128], sc_m[2][128], sc_s[2][128];
  const int b = blockIdx.z;
  float* C = e + (size_t)b * NN * NN;
  const int row0 = blockIdx.y * 128, col0 = blockIdx.x * 128;
  const int t = threadIdx.x;
  const int l = t & 63, w = t >> 6;
  const int wr = w >> 1, wc = w & 1;
  const int g = l >> 4, li = l & 15;
  const int wb = t & ~63;               // wave-uniform unit base

  if (t < 128) pmk[t] = p_mask[(size_t)b * NN + row0 + t];
  else hmk[t - 128] = h_mask[(size_t)b * NN + col0 + (t - 128)];

  const uint4* gAh = Ahg + ((size_t)(b * 4 + blockIdx.y) * 16) * 512;
  const uint4* gAl = Alg + ((size_t)(b * 4 + blockIdx.y) * 16) * 512;
  const uint4* gBh = Bhg + ((size_t)(b * 4 + blockIdx.x) * 16) * 512;
  const uint4* gBl = Blg + ((size_t)(b * 4 + blockIdx.x) * 16) * 512;

  f32x4 acc[4][4];
#pragma unroll
  for (int i = 0; i < 4; ++i)
#pragma unroll
    for (int j = 0; j < 4; ++j)
#pragma unroll
      for (int r = 0; r < 4; ++r) acc[i][j][r] = 0.f;

  for (int ks = 0; ks < 16; ++ks) {
    const int o = ks * 512;
    // ---- async stage: 8 x global_load_lds (16B/lane), linear layout ----
    gload16(&gAh[o + t],       &u.s.Ah[wb]);
    gload16(&gAh[o + 256 + t], &u.s.Ah[256 + wb]);
    gload16(&gAl[o + t],       &u.s.Al[wb]);
    gload16(&gAl[o + 256 + t], &u.s.Al[256 + wb]);
    gload16(&gBh[o + t],       &u.s.Bh[wb]);
    gload16(&gBh[o + 256 + t], &u.s.Bh[256 + wb]);
    gload16(&gBl[o + t],       &u.s.Bl[wb]);
    gload16(&gBl[o + 256 + t], &u.s.Bl[256 + wb]);
    __syncthreads();

    // pass 1: al . bh
    {
      bf16x8 fa[4], fb[4];
#pragma unroll
      for (int i = 0; i < 4; ++i) {
        fa[i] = *(const bf16x8*)&u.s.Al[(wr * 4 + i) * 64 + l];
        fb[i] = *(const bf16x8*)&u.s.Bh[(wc * 4 + i) * 64 + l];
      }
#pragma unroll
      for (int i = 0; i < 4; ++i)
#pragma unroll
        for (int j = 0; j < 4; ++j)
          acc[i][j] = __builtin_amdgcn_mfma_f32_16x16x32_bf16(fa[i], fb[j], acc[i][j], 0, 0, 0);
    }
    // pass 2: ah . bl
    {
      bf16x8 fa[4], fb[4];
#pragma unroll
      for (int i = 0; i < 4; ++i) {
        fa[i] = *(const bf16x8*)&u.s.Ah[(wr * 4 + i) * 64 + l];
        fb[i] = *(const bf16x8*)&u.s.Bl[(wc * 4 + i) * 64 + l];
      }
#pragma unroll
      for (int i = 0; i < 4; ++i)
#pragma unroll
        for (int j = 0; j < 4; ++j)
          acc[i][j] = __builtin_amdgcn_mfma_f32_16x16x32_bf16(fa[i], fb[j], acc[i][j], 0, 0, 0);
    }
    // pass 3: ah . bh
    {
      bf16x8 fa[4], fb[4];
#pragma unroll
      for (int i = 0; i < 4; ++i) {
        fa[i] = *(const bf16x8*)&u.s.Ah[(wr * 4 + i) * 64 + l];
        fb[i] = *(const bf16x8*)&u.s.Bh[(wc * 4 + i) * 64 + l];
      }
#pragma unroll
      for (int i = 0; i < 4; ++i)
#pragma unroll
        for (int j = 0; j < 4; ++j)
          acc[i][j] = __builtin_amdgcn_mfma_f32_16x16x32_bf16(fa[i], fb[j], acc[i][j], 0, 0, 0);
    }
    __syncthreads();
  }

  // ---- row stats (softmax over h): max & sum(exp) over this block's 128 cols
#pragma unroll
  for (int i = 0; i < 4; ++i)
#pragma unroll
    for (int r = 0; r < 4; ++r) {
      float v[4];
      float m = -INFINITY;
#pragma unroll
      for (int j = 0; j < 4; ++j) {
        v[j] = hmk[wc * 64 + j * 16 + li] ? -INFINITY : acc[i][j][r];
        m = fmaxf(m, v[j]);
      }
#pragma unroll
      for (int o = 1; o < 16; o <<= 1) m = fmaxf(m, __shfl_xor(m, o));
      float s = 0.f;
#pragma unroll
      for (int j = 0; j < 4; ++j) s += (v[j] == -INFINITY) ? 0.f : __expf(v[j] - m);
#pragma unroll
      for (int o = 1; o < 16; o <<= 1) s += __shfl_xor(s, o);
      if (li == 0) {
        st_m[wc][wr * 64 + i * 16 + g * 4 + r] = m;
        st_s[wc][wr * 64 + i * 16 + g * 4 + r] = s;
      }
    }

  // ---- col stats (softmax over p): max & sum(exp) over this block's 128 rows
#pragma unroll
  for (int j = 0; j < 4; ++j) {
    float v[16];
    float m = -INFINITY;
#pragma unroll
    for (int i = 0; i < 4; ++i)
#pragma unroll
      for (int r = 0; r < 4; ++r) {
        float x = pmk[wr * 64 + i * 16 + g * 4 + r] ? -INFINITY : acc[i][j][r];
        v[i * 4 + r] = x;
        m = fmaxf(m, x);
      }
    m = fmaxf(m, __shfl_xor(m, 16));
    m = fmaxf(m, __shfl_xor(m, 32));
    float s = 0.f;
#pragma unroll
    for (int q = 0; q < 16; ++q) s += (v[q] == -INFINITY) ? 0.f : __expf(v[q] - m);
    s += __shfl_xor(s, 16);
    s += __shfl_xor(s, 32);
    if (g == 0) {
      sc_m[wr][wc * 64 + j * 16 + li] = m;
      sc_s[wr][wc * 64 + j * 16 + li] = s;
    }
  }
  __syncthreads();

  if (t < 128) {
    float m0 = st_m[0][t], m1 = st_m[1][t];
    float s0 = st_s[0][t], s1 = st_s[1][t];
    float m = fmaxf(m0, m1);
    float s = 0.f;
    if (s0 > 0.f) s += s0 * __expf(m0 - m);
    if (s1 > 0.f) s += s1 * __expf(m1 - m);
    rpm[((size_t)b * 4 + blockIdx.x) * NN + row0 + t] = m;
    rps[((size_t)b * 4 + blockIdx.x) * NN + row0 + t] = s;
  } else {
    int c = t - 128;
    float m0 = sc_m[0][c], m1 = sc_m[1][c];
    float s0 = sc_s[0][c], s1 = sc_s[1][c];
    float m = fmaxf(m0, m1);
    float s = 0.f;
    if (s0 > 0.f) s += s0 * __expf(m0 - m);
    if (s1 > 0.f) s += s1 * __expf(m1 - m);
    cpm[((size_t)b * 4 + blockIdx.y) * NN + col0 + c] = m;
    cps[((size_t)b * 4 + blockIdx.y) * NN + col0 + c] = s;
  }

  // ---- E write via LDS bounce -> coalesced float4 stores ----
#pragma unroll
  for (int pass = 0; pass < 2; ++pass) {
    __syncthreads();
    if (wr == pass) {
#pragma unroll
      for (int i = 0; i < 4; ++i)
#pragma unroll
        for (int j = 0; j < 4; ++j)
#pragma unroll
          for (int r = 0; r < 4; ++r)
            u.ep[i * 16 + g * 4 + r][wc * 64 + j * 16 + li] = acc[i][j][r];
    }
    __syncthreads();
#pragma unroll
    for (int i = 0; i < 8; ++i) {
      int idx = i * 256 + t;
      int r = idx >> 5, c4 = idx & 31;
      int grow = row0 + pass * 64 + r;
      float4 v = *(const float4*)&u.ep[r][c4 * 4];
      *(float4*)&C[(size_t)grow * NN + col0 + c4 * 4] = v;
    }
  }
}

// --- Kernel 2: merge 4 partials per row/col (online-softmax merge) ---------
__global__ __launch_bounds__(512) void merge_stats(
    const float* __restrict__ rpm, const float* __restrict__ rps,
    const float* __restrict__ cpm, const float* __restrict__ cps,
    float* __restrict__ rmax, float* __restrict__ rinv,
    float* __restrict__ cmax, float* __restrict__ cinv) {
  const int b = blockIdx.x;
  const int t = threadIdx.x;
  const float* pm = blockIdx.y == 0 ? rpm : cpm;
  const float* ps = blockIdx.y == 0 ? rps : cps;
  float* fm = blockIdx.y == 0 ? rmax : cmax;
  float* fi = blockIdx.y == 0 ? rinv : cinv;
  float mj[4], sj[4];
  float m = -INFINITY;
#pragma unroll
  for (int j = 0; j < 4; ++j) {
    mj[j] = pm[((size_t)b * 4 + j) * NN + t];
    sj[j] = ps[((size_t)b * 4 + j) * NN + t];
    m = fmaxf(m, mj[j]);
  }
  float s = 0.f;
#pragma unroll
  for (int j = 0; j < 4; ++j)
    if (sj[j] > 0.f) s += sj[j] * __expf(mj[j] - m);
  fm[(size_t)b * NN + t] = m;
  fi[(size_t)b * NN + t] = 1.0f / s;
}

// --- Kernel 3: m_p : px_hat = softmax_h(e) @ hx, weights computed on the fly
__global__ __launch_bounds__(256) void gemm_wp(
    const float* __restrict__ E, const float* __restrict__ hxg,
    const float* __restrict__ pxg, const int* __restrict__ h_mask,
    const float* __restrict__ rmax, const float* __restrict__ rinv,
    float* __restrict__ outg) {
  __shared__ union {
    struct { char A[16384]; char B[16384]; } s;
    float ep[64][132];
  } u;
  const int b = blockIdx.z;
  const float* Eb = E + (size_t)b * NN * NN;
  const float* B = hxg + (size_t)b * NN * NN;
  const float* X = pxg + (size_t)b * NN * NN;
  const int* hm = h_mask + (size_t)b * NN;
  const float* rmx = rmax + (size_t)b * NN;
  const float* rin = rinv + (size_t)b * NN;
  float* out = outg + (size_t)b * NN * ROWC;
  const int row0 = blockIdx.y * 128, col0 = blockIdx.x * 128;
  const int t = threadIdx.x;
  const int l = t & 63, w = t >> 6;
  const int wr = w >> 1, wc = w & 1;

  float rmv[8];
#pragma unroll
  for (int i = 0; i < 8; ++i) rmv[i] = rmx[row0 + ((i * 256 + t) >> 4)];

  f32x4 acc[4][4];
#pragma unroll
  for (int i = 0; i < 4; ++i)
#pragma unroll
    for (int j = 0; j < 4; ++j)
#pragma unroll
      for (int r = 0; r < 4; ++r) acc[i][j][r] = 0.f;

  for (int k0 = 0; k0 < NN; k0 += 64) {
#pragma unroll
    for (int i = 0; i < 8; ++i) {
      int idx = i * 256 + t;
      int r = idx >> 4, c4 = idx & 15, k = c4 << 2;
      float4 f = *(const float4*)&Eb[(size_t)(row0 + r) * NN + k0 + k];
      int4 m4 = *(const int4*)&hm[k0 + k];
      float w0 = m4.x ? 0.f : __expf(f.x - rmv[i]);
      float w1 = m4.y ? 0.f : __expf(f.y - rmv[i]);
      float w2 = m4.z ? 0.f : __expf(f.z - rmv[i]);
      float w3 = m4.w ? 0.f : __expf(f.w - rmv[i]);
      unsigned int p01 = bf16_rne(w0) | (bf16_rne(w1) << 16);
      unsigned int p23 = bf16_rne(w2) | (bf16_rne(w3) << 16);
      int khalf = k >> 5, k8 = (k >> 3) & 3, j = k & 7;
      int byte = frag_byte(r >> 4, (r & 15) + (k8 << 4), khalf) + (j << 1);
      *(uint2*)&u.s.A[byte] = make_uint2(p01, p23);
    }
#pragma unroll
    for (int i = 0; i < 4; ++i) {
      int idx = i * 256 + t;
      int kp = idx >> 5, nq = idx & 31;
      int k = kp << 1, n = nq << 2;
      const float* p0 = &B[(size_t)(k0 + k) * NN + col0 + n];
      float4 f0 = *(const float4*)p0;
      float4 f1 = *(const float4*)(p0 + NN);
      int khalf = k >> 5, k8 = (k >> 3) & 3, j = k & 7;
      float fa0[4] = {f0.x, f0.y, f0.z, f0.w};
      float fa1[4] = {f1.x, f1.y, f1.z, f1.w};
#pragma unroll
      for (int c = 0; c < 4; ++c) {
        unsigned int pk = bf16_rne(fa0[c]) | (bf16_rne(fa1[c]) << 16);
        int nn2 = n + c;
        int byte = frag_byte(nn2 >> 4, (nn2 & 15) + (k8 << 4), khalf) + (j << 1);
        *(unsigned int*)&u.s.B[byte] = pk;
      }
    }
    __syncthreads();
#pragma unroll
    for (int kh = 0; kh < 2; ++kh) {
      bf16x8 av[4], bv[4];
#pragma unroll
      for (int i = 0; i < 4; ++i) {
        av[i] = *(const bf16x8*)&u.s.A[frag_byte(wr * 4 + i, l, kh)];
        bv[i] = *(const bf16x8*)&u.s.B[frag_byte(wc * 4 + i, l, kh)];
      }
#pragma unroll
      for (int i = 0; i < 4; ++i)
#pragma unroll
        for (int j = 0; j < 4; ++j)
          acc[i][j] = __builtin_amdgcn_mfma_f32_16x16x32_bf16(av[i], bv[j], acc[i][j], 0, 0, 0);
    }
    __syncthreads();
  }

  const int g = l >> 4, li = l & 15;
#pragma unroll
  for (int pass = 0; pass < 2; ++pass) {
    if (wr == pass) {
#pragma unroll
      for (int i = 0; i < 4; ++i)
#pragma unroll
        for (int j = 0; j < 4; ++j)
#pragma unroll
          for (int r = 0; r < 4; ++r)
            u.ep[i * 16 + g * 4 + r][wc * 64 + j * 16 + li] = acc[i][j][r];
    }
    __syncthreads();
#pragma unroll
    for (int i = 0; i < 8; ++i) {
      int idx = i * 256 + t;
      int r = idx >> 5, c4 = idx & 31;
      int grow = row0 + pass * 64 + r;
      float ri = rin[grow];
      float4 ph = *(const float4*)&u.ep[r][c4 * 4];
      ph.x *= ri; ph.y *= ri; ph.z *= ri; ph.w *= ri;
      float4 xv = *(const float4*)&X[(size_t)grow * NN + col0 + c4 * 4];
      size_t base = (size_t)grow * ROWC + col0 + c4 * 4;
      *(float4*)&out[base] = xv;
      *(float4*)&out[base + 512] = ph;
      float4 df = {xv.x - ph.x, xv.y - ph.y, xv.z - ph.z, xv.w - ph.w};
      *(float4*)&out[base + 1024] = df;
      float4 pr = {xv.x * ph.x, xv.y * ph.y, xv.z * ph.z, xv.w * ph.w};
      *(float4*)&out[base + 1536] = pr;
    }
    __syncthreads();
  }
}

// --- Kernel 4: m_h : hx_hat = softmax_p(e)^T @ px, weights on the fly ------
__global__ __launch_bounds__(256) void gemm_wh(
    const float* __restrict__ E, const float* __restrict__ pxg,
    const float* __restrict__ hxg, const int* __restrict__ p_mask,
    const float* __restrict__ cmax, const float* __restrict__ cinv,
    float* __restrict__ outg) {
  __shared__ union {
    struct { char A[16384]; char B[16384]; } s;
    float ep[64][132];
  } u;
  const int b = blockIdx.z;
  const float* Eb = E + (size_t)b * NN * NN;
  const float* B = pxg + (size_t)b * NN * NN;
  const float* X = hxg + (size_t)b * NN * NN;
  const int* pmsk = p_mask + (size_t)b * NN;
  const float* cmx = cmax + (size_t)b * NN;
  const float* cin = cinv + (size_t)b * NN;
  float* out = outg + (size_t)b * NN * ROWC;
  const int row0 = blockIdx.y * 128, col0 = blockIdx.x * 128;  // rows = h
  const int t = threadIdx.x;
  const int l = t & 63, w = t >> 6;
  const int wr = w >> 1, wc = w & 1;

  float4 cmv[4];
#pragma unroll
  for (int i = 0; i < 4; ++i) {
    int idx = i * 256 + t;
    int n = (idx & 31) << 2;
    cmv[i] = *(const float4*)&cmx[row0 + n];
  }

  f32x4 acc[4][4];
#pragma unroll
  for (int i = 0; i < 4; ++i)
#pragma unroll
    for (int j = 0; j < 4; ++j)
#pragma unroll
      for (int r = 0; r < 4; ++r) acc[i][j][r] = 0.f;

  for (int k0 = 0; k0 < NN; k0 += 64) {
#pragma unroll
    for (int i = 0; i < 4; ++i) {
      int idx = i * 256 + t;
      int kp = idx >> 5, nq = idx & 31;
      int k = kp << 1, n = nq << 2;
      const float* p0 = &Eb[(size_t)(k0 + k) * NN + row0 + n];
      float4 f0 = *(const float4*)p0;
      float4 f1 = *(const float4*)(p0 + NN);
      int pm0 = pmsk[k0 + k], pm1 = pmsk[k0 + k + 1];
      float fa0[4] = {f0.x, f0.y, f0.z, f0.w};
      float fa1[4] = {f1.x, f1.y, f1.z, f1.w};
      float cma[4] = {cmv[i].x, cmv[i].y, cmv[i].z, cmv[i].w};
      int khalf = k >> 5, k8 = (k >> 3) & 3, j = k & 7;
#pragma unroll
      for (int c = 0; c < 4; ++c) {
        float w0 = pm0 ? 0.f : __expf(fa0[c] - cma[c]);
        float w1 = pm1 ? 0.f : __expf(fa1[c] - cma[c]);
        unsigned int pk = bf16_rne(w0) | (bf16_rne(w1) << 16);
        int nn2 = n + c;
        int byte = frag_byte(nn2 >> 4, (nn2 & 15) + (k8 << 4), khalf) + (j << 1);
        *(unsigned int*)&u.s.A[byte] = pk;
      }
    }
#pragma unroll
    for (int i = 0; i < 4; ++i) {
      int idx = i * 256 + t;
      int kp = idx >> 5, nq = idx & 31;
      int k = kp << 1, n = nq << 2;
      const float* p0 = &B[(size_t)(k0 + k) * NN + col0 + n];
      float4 f0 = *(const float4*)p0;
      float4 f1 = *(const float4*)(p0 + NN);
      int khalf = k >> 5, k8 = (k >> 3) & 3, j = k & 7;
      float fa0[4] = {f0.x, f0.y, f0.z, f0.w};
      float fa1[4] = {f1.x, f1.y, f1.z, f1.w};
#pragma unroll
      for (int c = 0; c < 4; ++c) {
        unsigned int pk = bf16_rne(fa0[c]) | (bf16_rne(fa1[c]) << 16);
        int nn2 = n + c;
        int byte = frag_byte(nn2 >> 4, (nn2 & 15) + (k8 << 4), khalf) + (j << 1);
        *(unsigned int*)&u.s.B[byte] = pk;
      }
    }
    __syncthreads();
#pragma unroll
    for (int kh = 0; kh < 2; ++kh) {
      bf16x8 av[4], bv[4];
#pragma unroll
      for (int i = 0; i < 4; ++i) {
        av[i] = *(const bf16x8*)&u.s.A[frag_byte(wr * 4 + i, l, kh)];
        bv[i] = *(const bf16x8*)&u.s.B[frag_byte(wc * 4 + i, l, kh)];
      }
#pragma unroll
      for (int i = 0; i < 4; ++i)
#pragma unroll
        for (int j = 0; j < 4; ++j)
          acc[i][j] = __builtin_amdgcn_mfma_f32_16x16x32_bf16(av[i], bv[j], acc[i][j], 0, 0, 0);
    }
    __syncthreads();
  }

  const int g = l >> 4, li = l & 15;
#pragma unroll
  for (int pass = 0; pass < 2; ++pass) {
    if (wr == pass) {
#pragma unroll
      for (int i = 0; i < 4; ++i)
#pragma unroll
        for (int j = 0; j < 4; ++j)
#pragma unroll
          for (int r = 0; r < 4; ++r)
            u.ep[i * 16 + g * 4 + r][wc * 64 + j * 16 + li] = acc[i][j][r];
    }
    __syncthreads();
#pragma unroll
    for (int i = 0; i < 8; ++i) {
      int idx = i * 256 + t;
      int r = idx >> 5, c4 = idx & 31;
      int grow = row0 + pass * 64 + r;  // h
      float ci = cin[grow];
      float4 hh = *(const float4*)&u.ep[r][c4 * 4];
      hh.x *= ci; hh.y *= ci; hh.z *= ci; hh.w *= ci;
      float4 xv = *(const float4*)&X[(size_t)grow * NN + col0 + c4 * 4];
      size_t base = (size_t)grow * ROWC + col0 + c4 * 4;
      *(float4*)&out[base] = xv;
      *(float4*)&out[base + 512] = hh;
      float4 df = {xv.x - hh.x, xv.y - hh.y, xv.z - hh.z, xv.w - hh.w};
      *(float4*)&out[base + 1024] = df;
      float4 pr = {xv.x * hh.x, xv.y * hh.y, xv.z * hh.z, xv.w * hh.w};
      *(float4*)&out[base + 1536] = pr;
    }
    __syncthreads();
  }
}

extern "C" void kernel_launch(void* const* d_in, const int* in_sizes, int n_in,
                              void* d_out, int out_size, void* d_ws, size_t ws_size,
                              hipStream_t stream) {
  const float* px = (const float*)d_in[0];
  const float* hx = (const float*)d_in[1];
  const int* p_mask = (const int*)d_in[2];
  const int* h_mask = (const int*)d_in[3];
  float* out = (float*)d_out;

  const size_t NE = (size_t)NB * NN * NN;          // 8.4M elements
  const size_t NU = (size_t)NB * 4 * 16 * 512;     // uint4 units per array
  float* E = (float*)d_ws;                         // 33.5 MB fp32
  uint4* pxh = (uint4*)(E + NE);                   // 4 x 16.8 MB tiled bf16
  uint4* pxl = pxh + NU;
  uint4* hxh = pxl + NU;
  uint4* hxl = hxh + NU;
  float* rpm = (float*)(hxl + NU);                 // [B][4][NN] partials
  float* rps = rpm + (size_t)NB * 4 * NN;
  float* cpm = rps + (size_t)NB * 4 * NN;
  float* cps = cpm + (size_t)NB * 4 * NN;
  float* rmaxv = cps + (size_t)NB * 4 * NN;        // [B][NN] finals
  float* rinvv = rmaxv + (size_t)NB * NN;
  float* cmaxv = rinvv + (size_t)NB * NN;
  float* cinvv = cmaxv + (size_t)NB * NN;

  dim3 gg(4, 4, NB);
  convert_tiled<<<dim3(128, 2), dim3(256), 0, stream>>>(px, hx, pxh, pxl, hxh, hxl);
  gemm_e_stats<<<gg, dim3(256), 0, stream>>>(pxh, pxl, hxh, hxl, p_mask, h_mask,
                                             E, rpm, rps, cpm, cps);
  merge_stats<<<dim3(NB, 2), dim3(512), 0, stream>>>(rpm, rps, cpm, cps,
                                                     rmaxv, rinvv, cmaxv, cinvv);
  gemm_wp<<<gg, dim3(256), 0, stream>>>(E, hx, px, h_mask, rmaxv, rinvv, out);
  gemm_wh<<<gg, dim3(256), 0, stream>>>(E, px, hx, p_mask, cmaxv, cinvv,
                                        out + (size_t)NB * NN * ROWC);
}

// Round 19
// 202.572 us; speedup vs baseline: 1.0325x; 1.0325x over previous
//
#include <hip/hip_runtime.h>
#include <math.h>

#define NB 32
#define NN 512
#define ROWC 2048ull

typedef __attribute__((ext_vector_type(8))) short bf16x8;
typedef __attribute__((ext_vector_type(4))) float f32x4;

__device__ __forceinline__ unsigned int fbits(float f) {
  union { float f; unsigned int u; } v; v.f = f; return v.u;
}
__device__ __forceinline__ float bcast(unsigned int u) {
  union { unsigned int u; float f; } v; v.u = u; return v.f;
}
// round-to-nearest-even bf16, returned in low 16 bits
__device__ __forceinline__ unsigned int bf16_rne(float f) {
  unsigned int b = fbits(f);
  return (b + 0x7FFFu + ((b >> 16) & 1u)) >> 16;
}

// Fragment-ordered LDS address (BK=64 form) used by gemm_wp / gemm_wh.
__device__ __forceinline__ int frag_byte(int blk, int lane, int khalf) {
  int base = ((((khalf << 3) + blk) << 6) + lane) << 4;
  int swz = (blk ^ (lane >> 4) ^ (khalf << 2)) & 7;
  return base ^ (swz << 4);
}

// --- Kernel 0: fp32 -> hi/lo bf16, PRE-TILED in MFMA fragment order --------
__global__ __launch_bounds__(256) void convert_tiled(
    const float* __restrict__ px, const float* __restrict__ hx,
    uint4* __restrict__ pxh, uint4* __restrict__ pxl,
    uint4* __restrict__ hxh, uint4* __restrict__ hxl) {
  const int bp = blockIdx.x;            // b*4 + P, 0..127
  const float* src = (blockIdx.y ? hx : px) + (size_t)bp * 128 * NN;
  uint4* dh = (blockIdx.y ? hxh : pxh) + (size_t)bp * 16 * 512;
  uint4* dl = (blockIdx.y ? hxl : pxl) + (size_t)bp * 16 * 512;
  const int t = threadIdx.x;
#pragma unroll
  for (int i = 0; i < 8; ++i) {
    int idx = i * 256 + t;              // 0..2047 = (ks, row)
    int ks = idx >> 7, row = idx & 127;
    const float* rp = src + (size_t)row * NN + ks * 32;
    int ub = ks * 512 + (row >> 4) * 64 + (row & 15);
#pragma unroll
    for (int ko = 0; ko < 4; ++ko) {
      float4 f0 = *(const float4*)(rp + ko * 8);
      float4 f1 = *(const float4*)(rp + ko * 8 + 4);
      float ff[8] = {f0.x, f0.y, f0.z, f0.w, f1.x, f1.y, f1.z, f1.w};
      union { unsigned short us[8]; uint4 u4; } hi, lo;
#pragma unroll
      for (int q = 0; q < 8; ++q) {
        unsigned int bq = fbits(ff[q]);
        hi.us[q] = (unsigned short)(bq >> 16);
        float r = ff[q] - bcast(bq & 0xFFFF0000u);
        lo.us[q] = (unsigned short)(fbits(r) >> 16);
      }
      dh[ub + 16 * ko] = hi.u4;
      dl[ub + 16 * ko] = lo.u4;
    }
  }
}

// --- Kernel 1: e = px.hx^T (3-term split) + fused masked row/col stats -----
// EXACT r16 dataflow (ping-pong register prefetch, 2 barriers/step — the
// only pipelined variant that passed). ONLY change: batch-coherent XCD
// swizzle (id = 128q + 8*tile + rr, b = 8q+rr): all 16 tiles of a batch
// (2MB of hi/lo panels, L2-sized) land on ONE XCD instead of being sprayed
// round-robin across 8.
__global__ __launch_bounds__(256) void gemm_e_stats(
    const uint4* __restrict__ Ahg, const uint4* __restrict__ Alg,
    const uint4* __restrict__ Bhg, const uint4* __restrict__ Blg,
    const int* __restrict__ p_mask, const int* __restrict__ h_mask,
    float* __restrict__ e,
    float* __restrict__ rpm, float* __restrict__ rps,
    float* __restrict__ cpm, float* __restrict__ cps) {
  __shared__ union {
    struct { uint4 Ah[512]; uint4 Al[512]; uint4 Bh[512]; uint4 Bl[512]; } s;
    float ep[64][132];
  } u;
  __shared__ int pmk[128], hmk[128];
  __shared__ float st_m[2][128], st_s[2][128], sc_m[2][128], sc_s[2][128];

  // batch-coherent XCD swizzle decode (bijective: verified id=128q+8*tile+rr)
  const int id = blockIdx.x;
  const int q = id >> 7, rr = id & 7, tile = (id >> 3) & 15;
  const int b = q * 8 + rr;
  const int bx = tile & 3, by = tile >> 2;

  float* C = e + (size_t)b * NN * NN;
  const int row0 = by * 128, col0 = bx * 128;
  const int t = threadIdx.x;
  const int l = t & 63, w = t >> 6;
  const int wr = w >> 1, wc = w & 1;
  const int g = l >> 4, li = l & 15;

  if (t < 128) pmk[t] = p_mask[(size_t)b * NN + row0 + t];
  else hmk[t - 128] = h_mask[(size_t)b * NN + col0 + (t - 128)];

  const uint4* gAh = Ahg + ((size_t)(b * 4 + by) * 16) * 512;
  const uint4* gAl = Alg + ((size_t)(b * 4 + by) * 16) * 512;
  const uint4* gBh = Bhg + ((size_t)(b * 4 + bx) * 16) * 512;
  const uint4* gBl = Blg + ((size_t)(b * 4 + bx) * 16) * 512;

  f32x4 acc[4][4];
#pragma unroll
  for (int i = 0; i < 4; ++i)
#pragma unroll
    for (int j = 0; j < 4; ++j)
#pragma unroll
      for (int r = 0; r < 4; ++r) acc[i][j][r] = 0.f;

  // MFMA over the currently staged LDS tile (3-term split)
  auto do_mfma = [&]() {
    {
      bf16x8 fa[4], fb[4];
#pragma unroll
      for (int i = 0; i < 4; ++i) {
        fa[i] = *(const bf16x8*)&u.s.Al[(wr * 4 + i) * 64 + l];
        fb[i] = *(const bf16x8*)&u.s.Bh[(wc * 4 + i) * 64 + l];
      }
#pragma unroll
      for (int i = 0; i < 4; ++i)
#pragma unroll
        for (int j = 0; j < 4; ++j)
          acc[i][j] = __builtin_amdgcn_mfma_f32_16x16x32_bf16(fa[i], fb[j], acc[i][j], 0, 0, 0);
    }
    {
      bf16x8 fa[4], fb[4];
#pragma unroll
      for (int i = 0; i < 4; ++i) {
        fa[i] = *(const bf16x8*)&u.s.Ah[(wr * 4 + i) * 64 + l];
        fb[i] = *(const bf16x8*)&u.s.Bl[(wc * 4 + i) * 64 + l];
      }
#pragma unroll
      for (int i = 0; i < 4; ++i)
#pragma unroll
        for (int j = 0; j < 4; ++j)
          acc[i][j] = __builtin_amdgcn_mfma_f32_16x16x32_bf16(fa[i], fb[j], acc[i][j], 0, 0, 0);
    }
    {
      bf16x8 fa[4], fb[4];
#pragma unroll
      for (int i = 0; i < 4; ++i) {
        fa[i] = *(const bf16x8*)&u.s.Ah[(wr * 4 + i) * 64 + l];
        fb[i] = *(const bf16x8*)&u.s.Bh[(wc * 4 + i) * 64 + l];
      }
#pragma unroll
      for (int i = 0; i < 4; ++i)
#pragma unroll
        for (int j = 0; j < 4; ++j)
          acc[i][j] = __builtin_amdgcn_mfma_f32_16x16x32_bf16(fa[i], fb[j], acc[i][j], 0, 0, 0);
    }
  };

  // ---- ping-pong register sets (r16, proven correct) ----
  uint4 aA0, aA1, aL0, aL1, aB0, aB1, aM0, aM1;   // set A (even steps)
  uint4 bA0, bA1, bL0, bL1, bB0, bB1, bM0, bM1;   // set B (odd steps)

  aA0 = gAh[t];  aA1 = gAh[t + 256];
  aL0 = gAl[t];  aL1 = gAl[t + 256];
  aB0 = gBh[t];  aB1 = gBh[t + 256];
  aM0 = gBl[t];  aM1 = gBl[t + 256];

  for (int ks = 0; ks < 16; ks += 2) {
    // ---- EVEN phase: stage set A, prefetch set B (ks+1) ----
    u.s.Ah[t] = aA0;  u.s.Ah[t + 256] = aA1;
    u.s.Al[t] = aL0;  u.s.Al[t + 256] = aL1;
    u.s.Bh[t] = aB0;  u.s.Bh[t + 256] = aB1;
    u.s.Bl[t] = aM0;  u.s.Bl[t + 256] = aM1;
    __syncthreads();
    {
      const int o = (ks + 1) * 512;
      bA0 = gAh[o + t];  bA1 = gAh[o + t + 256];
      bL0 = gAl[o + t];  bL1 = gAl[o + t + 256];
      bB0 = gBh[o + t];  bB1 = gBh[o + t + 256];
      bM0 = gBl[o + t];  bM1 = gBl[o + t + 256];
    }
    do_mfma();
    __syncthreads();

    // ---- ODD phase: stage set B, prefetch set A (ks+2) ----
    u.s.Ah[t] = bA0;  u.s.Ah[t + 256] = bA1;
    u.s.Al[t] = bL0;  u.s.Al[t + 256] = bL1;
    u.s.Bh[t] = bB0;  u.s.Bh[t + 256] = bB1;
    u.s.Bl[t] = bM0;  u.s.Bl[t + 256] = bM1;
    __syncthreads();
    if (ks + 2 < 16) {
      const int o = (ks + 2) * 512;
      aA0 = gAh[o + t];  aA1 = gAh[o + t + 256];
      aL0 = gAl[o + t];  aL1 = gAl[o + t + 256];
      aB0 = gBh[o + t];  aB1 = gBh[o + t + 256];
      aM0 = gBl[o + t];  aM1 = gBl[o + t + 256];
    }
    do_mfma();
    __syncthreads();
  }

  // ---- row stats (softmax over h): max & sum(exp) over this block's 128 cols
#pragma unroll
  for (int i = 0; i < 4; ++i)
#pragma unroll
    for (int r = 0; r < 4; ++r) {
      float v[4];
      float m = -INFINITY;
#pragma unroll
      for (int j = 0; j < 4; ++j) {
        v[j] = hmk[wc * 64 + j * 16 + li] ? -INFINITY : acc[i][j][r];
        m = fmaxf(m, v[j]);
      }
#pragma unroll
      for (int o = 1; o < 16; o <<= 1) m = fmaxf(m, __shfl_xor(m, o));
      float s = 0.f;
#pragma unroll
      for (int j = 0; j < 4; ++j) s += (v[j] == -INFINITY) ? 0.f : __expf(v[j] - m);
#pragma unroll
      for (int o = 1; o < 16; o <<= 1) s += __shfl_xor(s, o);
      if (li == 0) {
        st_m[wc][wr * 64 + i * 16 + g * 4 + r] = m;
        st_s[wc][wr * 64 + i * 16 + g * 4 + r] = s;
      }
    }

  // ---- col stats (softmax over p): max & sum(exp) over this block's 128 rows
#pragma unroll
  for (int j = 0; j < 4; ++j) {
    float v[16];
    float m = -INFINITY;
#pragma unroll
    for (int i = 0; i < 4; ++i)
#pragma unroll
      for (int r = 0; r < 4; ++r) {
        float x = pmk[wr * 64 + i * 16 + g * 4 + r] ? -INFINITY : acc[i][j][r];
        v[i * 4 + r] = x;
        m = fmaxf(m, x);
      }
    m = fmaxf(m, __shfl_xor(m, 16));
    m = fmaxf(m, __shfl_xor(m, 32));
    float s = 0.f;
#pragma unroll
    for (int qq = 0; qq < 16; ++qq) s += (v[qq] == -INFINITY) ? 0.f : __expf(v[qq] - m);
    s += __shfl_xor(s, 16);
    s += __shfl_xor(s, 32);
    if (g == 0) {
      sc_m[wr][wc * 64 + j * 16 + li] = m;
      sc_s[wr][wc * 64 + j * 16 + li] = s;
    }
  }
  __syncthreads();

  if (t < 128) {
    float m0 = st_m[0][t], m1 = st_m[1][t];
    float s0 = st_s[0][t], s1 = st_s[1][t];
    float m = fmaxf(m0, m1);
    float s = 0.f;
    if (s0 > 0.f) s += s0 * __expf(m0 - m);
    if (s1 > 0.f) s += s1 * __expf(m1 - m);
    rpm[((size_t)b * 4 + bx) * NN + row0 + t] = m;
    rps[((size_t)b * 4 + bx) * NN + row0 + t] = s;
  } else {
    int c = t - 128;
    float m0 = sc_m[0][c], m1 = sc_m[1][c];
    float s0 = sc_s[0][c], s1 = sc_s[1][c];
    float m = fmaxf(m0, m1);
    float s = 0.f;
    if (s0 > 0.f) s += s0 * __expf(m0 - m);
    if (s1 > 0.f) s += s1 * __expf(m1 - m);
    cpm[((size_t)b * 4 + by) * NN + col0 + c] = m;
    cps[((size_t)b * 4 + by) * NN + col0 + c] = s;
  }

  // ---- E write via LDS bounce -> coalesced float4 stores ----
#pragma unroll
  for (int pass = 0; pass < 2; ++pass) {
    __syncthreads();
    if (wr == pass) {
#pragma unroll
      for (int i = 0; i < 4; ++i)
#pragma unroll
        for (int j = 0; j < 4; ++j)
#pragma unroll
          for (int r = 0; r < 4; ++r)
            u.ep[i * 16 + g * 4 + r][wc * 64 + j * 16 + li] = acc[i][j][r];
    }
    __syncthreads();
#pragma unroll
    for (int i = 0; i < 8; ++i) {
      int idx = i * 256 + t;
      int r = idx >> 5, c4 = idx & 31;
      int grow = row0 + pass * 64 + r;
      float4 v = *(const float4*)&u.ep[r][c4 * 4];
      *(float4*)&C[(size_t)grow * NN + col0 + c4 * 4] = v;
    }
  }
}

// --- Kernel 2: merge 4 partials per row/col (online-softmax merge) ---------
__global__ __launch_bounds__(512) void merge_stats(
    const float* __restrict__ rpm, const float* __restrict__ rps,
    const float* __restrict__ cpm, const float* __restrict__ cps,
    float* __restrict__ rmax, float* __restrict__ rinv,
    float* __restrict__ cmax, float* __restrict__ cinv) {
  const int b = blockIdx.x;
  const int t = threadIdx.x;
  const float* pm = blockIdx.y == 0 ? rpm : cpm;
  const float* ps = blockIdx.y == 0 ? rps : cps;
  float* fm = blockIdx.y == 0 ? rmax : cmax;
  float* fi = blockIdx.y == 0 ? rinv : cinv;
  float mj[4], sj[4];
  float m = -INFINITY;
#pragma unroll
  for (int j = 0; j < 4; ++j) {
    mj[j] = pm[((size_t)b * 4 + j) * NN + t];
    sj[j] = ps[((size_t)b * 4 + j) * NN + t];
    m = fmaxf(m, mj[j]);
  }
  float s = 0.f;
#pragma unroll
  for (int j = 0; j < 4; ++j)
    if (sj[j] > 0.f) s += sj[j] * __expf(mj[j] - m);
  fm[(size_t)b * NN + t] = m;
  fi[(size_t)b * NN + t] = 1.0f / s;
}

// --- Kernel 3: m_p : px_hat = softmax_h(e) @ hx, weights computed on the fly
__global__ __launch_bounds__(256) void gemm_wp(
    const float* __restrict__ E, const float* __restrict__ hxg,
    const float* __restrict__ pxg, const int* __restrict__ h_mask,
    const float* __restrict__ rmax, const float* __restrict__ rinv,
    float* __restrict__ outg) {
  __shared__ union {
    struct { char A[16384]; char B[16384]; } s;
    float ep[64][132];
  } u;
  const int b = blockIdx.z;
  const float* Eb = E + (size_t)b * NN * NN;
  const float* B = hxg + (size_t)b * NN * NN;
  const float* X = pxg + (size_t)b * NN * NN;
  const int* hm = h_mask + (size_t)b * NN;
  const float* rmx = rmax + (size_t)b * NN;
  const float* rin = rinv + (size_t)b * NN;
  float* out = outg + (size_t)b * NN * ROWC;
  const int row0 = blockIdx.y * 128, col0 = blockIdx.x * 128;
  const int t = threadIdx.x;
  const int l = t & 63, w = t >> 6;
  const int wr = w >> 1, wc = w & 1;

  float rmv[8];
#pragma unroll
  for (int i = 0; i < 8; ++i) rmv[i] = rmx[row0 + ((i * 256 + t) >> 4)];

  f32x4 acc[4][4];
#pragma unroll
  for (int i = 0; i < 4; ++i)
#pragma unroll
    for (int j = 0; j < 4; ++j)
#pragma unroll
      for (int r = 0; r < 4; ++r) acc[i][j][r] = 0.f;

  for (int k0 = 0; k0 < NN; k0 += 64) {
#pragma unroll
    for (int i = 0; i < 8; ++i) {
      int idx = i * 256 + t;
      int r = idx >> 4, c4 = idx & 15, k = c4 << 2;
      float4 f = *(const float4*)&Eb[(size_t)(row0 + r) * NN + k0 + k];
      int4 m4 = *(const int4*)&hm[k0 + k];
      float w0 = m4.x ? 0.f : __expf(f.x - rmv[i]);
      float w1 = m4.y ? 0.f : __expf(f.y - rmv[i]);
      float w2 = m4.z ? 0.f : __expf(f.z - rmv[i]);
      float w3 = m4.w ? 0.f : __expf(f.w - rmv[i]);
      unsigned int p01 = bf16_rne(w0) | (bf16_rne(w1) << 16);
      unsigned int p23 = bf16_rne(w2) | (bf16_rne(w3) << 16);
      int khalf = k >> 5, k8 = (k >> 3) & 3, j = k & 7;
      int byte = frag_byte(r >> 4, (r & 15) + (k8 << 4), khalf) + (j << 1);
      *(uint2*)&u.s.A[byte] = make_uint2(p01, p23);
    }
#pragma unroll
    for (int i = 0; i < 4; ++i) {
      int idx = i * 256 + t;
      int kp = idx >> 5, nq = idx & 31;
      int k = kp << 1, n = nq << 2;
      const float* p0 = &B[(size_t)(k0 + k) * NN + col0 + n];
      float4 f0 = *(const float4*)p0;
      float4 f1 = *(const float4*)(p0 + NN);
      int khalf = k >> 5, k8 = (k >> 3) & 3, j = k & 7;
      float fa0[4] = {f0.x, f0.y, f0.z, f0.w};
      float fa1[4] = {f1.x, f1.y, f1.z, f1.w};
#pragma unroll
      for (int c = 0; c < 4; ++c) {
        unsigned int pk = bf16_rne(fa0[c]) | (bf16_rne(fa1[c]) << 16);
        int nn2 = n + c;
        int byte = frag_byte(nn2 >> 4, (nn2 & 15) + (k8 << 4), khalf) + (j << 1);
        *(unsigned int*)&u.s.B[byte] = pk;
      }
    }
    __syncthreads();
#pragma unroll
    for (int kh = 0; kh < 2; ++kh) {
      bf16x8 av[4], bv[4];
#pragma unroll
      for (int i = 0; i < 4; ++i) {
        av[i] = *(const bf16x8*)&u.s.A[frag_byte(wr * 4 + i, l, kh)];
        bv[i] = *(const bf16x8*)&u.s.B[frag_byte(wc * 4 + i, l, kh)];
      }
#pragma unroll
      for (int i = 0; i < 4; ++i)
#pragma unroll
        for (int j = 0; j < 4; ++j)
          acc[i][j] = __builtin_amdgcn_mfma_f32_16x16x32_bf16(av[i], bv[j], acc[i][j], 0, 0, 0);
    }
    __syncthreads();
  }

  const int g = l >> 4, li = l & 15;
#pragma unroll
  for (int pass = 0; pass < 2; ++pass) {
    if (wr == pass) {
#pragma unroll
      for (int i = 0; i < 4; ++i)
#pragma unroll
        for (int j = 0; j < 4; ++j)
#pragma unroll
          for (int r = 0; r < 4; ++r)
            u.ep[i * 16 + g * 4 + r][wc * 64 + j * 16 + li] = acc[i][j][r];
    }
    __syncthreads();
#pragma unroll
    for (int i = 0; i < 8; ++i) {
      int idx = i * 256 + t;
      int r = idx >> 5, c4 = idx & 31;
      int grow = row0 + pass * 64 + r;
      float ri = rin[grow];
      float4 ph = *(const float4*)&u.ep[r][c4 * 4];
      ph.x *= ri; ph.y *= ri; ph.z *= ri; ph.w *= ri;
      float4 xv = *(const float4*)&X[(size_t)grow * NN + col0 + c4 * 4];
      size_t base = (size_t)grow * ROWC + col0 + c4 * 4;
      *(float4*)&out[base] = xv;
      *(float4*)&out[base + 512] = ph;
      float4 df = {xv.x - ph.x, xv.y - ph.y, xv.z - ph.z, xv.w - ph.w};
      *(float4*)&out[base + 1024] = df;
      float4 pr = {xv.x * ph.x, xv.y * ph.y, xv.z * ph.z, xv.w * ph.w};
      *(float4*)&out[base + 1536] = pr;
    }
    __syncthreads();
  }
}

// --- Kernel 4: m_h : hx_hat = softmax_p(e)^T @ px, weights on the fly ------
__global__ __launch_bounds__(256) void gemm_wh(
    const float* __restrict__ E, const float* __restrict__ pxg,
    const float* __restrict__ hxg, const int* __restrict__ p_mask,
    const float* __restrict__ cmax, const float* __restrict__ cinv,
    float* __restrict__ outg) {
  __shared__ union {
    struct { char A[16384]; char B[16384]; } s;
    float ep[64][132];
  } u;
  const int b = blockIdx.z;
  const float* Eb = E + (size_t)b * NN * NN;
  const float* B = pxg + (size_t)b * NN * NN;
  const float* X = hxg + (size_t)b * NN * NN;
  const int* pmsk = p_mask + (size_t)b * NN;
  const float* cmx = cmax + (size_t)b * NN;
  const float* cin = cinv + (size_t)b * NN;
  float* out = outg + (size_t)b * NN * ROWC;
  const int row0 = blockIdx.y * 128, col0 = blockIdx.x * 128;  // rows = h
  const int t = threadIdx.x;
  const int l = t & 63, w = t >> 6;
  const int wr = w >> 1, wc = w & 1;

  float4 cmv[4];
#pragma unroll
  for (int i = 0; i < 4; ++i) {
    int idx = i * 256 + t;
    int n = (idx & 31) << 2;
    cmv[i] = *(const float4*)&cmx[row0 + n];
  }

  f32x4 acc[4][4];
#pragma unroll
  for (int i = 0; i < 4; ++i)
#pragma unroll
    for (int j = 0; j < 4; ++j)
#pragma unroll
      for (int r = 0; r < 4; ++r) acc[i][j][r] = 0.f;

  for (int k0 = 0; k0 < NN; k0 += 64) {
#pragma unroll
    for (int i = 0; i < 4; ++i) {
      int idx = i * 256 + t;
      int kp = idx >> 5, nq = idx & 31;
      int k = kp << 1, n = nq << 2;
      const float* p0 = &Eb[(size_t)(k0 + k) * NN + row0 + n];
      float4 f0 = *(const float4*)p0;
      float4 f1 = *(const float4*)(p0 + NN);
      int pm0 = pmsk[k0 + k], pm1 = pmsk[k0 + k + 1];
      float fa0[4] = {f0.x, f0.y, f0.z, f0.w};
      float fa1[4] = {f1.x, f1.y, f1.z, f1.w};
      float cma[4] = {cmv[i].x, cmv[i].y, cmv[i].z, cmv[i].w};
      int khalf = k >> 5, k8 = (k >> 3) & 3, j = k & 7;
#pragma unroll
      for (int c = 0; c < 4; ++c) {
        float w0 = pm0 ? 0.f : __expf(fa0[c] - cma[c]);
        float w1 = pm1 ? 0.f : __expf(fa1[c] - cma[c]);
        unsigned int pk = bf16_rne(w0) | (bf16_rne(w1) << 16);
        int nn2 = n + c;
        int byte = frag_byte(nn2 >> 4, (nn2 & 15) + (k8 << 4), khalf) + (j << 1);
        *(unsigned int*)&u.s.A[byte] = pk;
      }
    }
#pragma unroll
    for (int i = 0; i < 4; ++i) {
      int idx = i * 256 + t;
      int kp = idx >> 5, nq = idx & 31;
      int k = kp << 1, n = nq << 2;
      const float* p0 = &B[(size_t)(k0 + k) * NN + col0 + n];
      float4 f0 = *(const float4*)p0;
      float4 f1 = *(const float4*)(p0 + NN);
      int khalf = k >> 5, k8 = (k >> 3) & 3, j = k & 7;
      float fa0[4] = {f0.x, f0.y, f0.z, f0.w};
      float fa1[4] = {f1.x, f1.y, f1.z, f1.w};
#pragma unroll
      for (int c = 0; c < 4; ++c) {
        unsigned int pk = bf16_rne(fa0[c]) | (bf16_rne(fa1[c]) << 16);
        int nn2 = n + c;
        int byte = frag_byte(nn2 >> 4, (nn2 & 15) + (k8 << 4), khalf) + (j << 1);
        *(unsigned int*)&u.s.B[byte] = pk;
      }
    }
    __syncthreads();
#pragma unroll
    for (int kh = 0; kh < 2; ++kh) {
      bf16x8 av[4], bv[4];
#pragma unroll
      for (int i = 0; i < 4; ++i) {
        av[i] = *(const bf16x8*)&u.s.A[frag_byte(wr * 4 + i, l, kh)];
        bv[i] = *(const bf16x8*)&u.s.B[frag_byte(wc * 4 + i, l, kh)];
      }
#pragma unroll
      for (int i = 0; i < 4; ++i)
#pragma unroll
        for (int j = 0; j < 4; ++j)
          acc[i][j] = __builtin_amdgcn_mfma_f32_16x16x32_bf16(av[i], bv[j], acc[i][j], 0, 0, 0);
    }
    __syncthreads();
  }

  const int g = l >> 4, li = l & 15;
#pragma unroll
  for (int pass = 0; pass < 2; ++pass) {
    if (wr == pass) {
#pragma unroll
      for (int i = 0; i < 4; ++i)
#pragma unroll
        for (int j = 0; j < 4; ++j)
#pragma unroll
          for (int r = 0; r < 4; ++r)
            u.ep[i * 16 + g * 4 + r][wc * 64 + j * 16 + li] = acc[i][j][r];
    }
    __syncthreads();
#pragma unroll
    for (int i = 0; i < 8; ++i) {
      int idx = i * 256 + t;
      int r = idx >> 5, c4 = idx & 31;
      int grow = row0 + pass * 64 + r;  // h
      float ci = cin[grow];
      float4 hh = *(const float4*)&u.ep[r][c4 * 4];
      hh.x *= ci; hh.y *= ci; hh.z *= ci; hh.w *= ci;
      float4 xv = *(const float4*)&X[(size_t)grow * NN + col0 + c4 * 4];
      size_t base = (size_t)grow * ROWC + col0 + c4 * 4;
      *(float4*)&out[base] = xv;
      *(float4*)&out[base + 512] = hh;
      float4 df = {xv.x - hh.x, xv.y - hh.y, xv.z - hh.z, xv.w - hh.w};
      *(float4*)&out[base + 1024] = df;
      float4 pr = {xv.x * hh.x, xv.y * hh.y, xv.z * hh.z, xv.w * hh.w};
      *(float4*)&out[base + 1536] = pr;
    }
    __syncthreads();
  }
}

extern "C" void kernel_launch(void* const* d_in, const int* in_sizes, int n_in,
                              void* d_out, int out_size, void* d_ws, size_t ws_size,
                              hipStream_t stream) {
  const float* px = (const float*)d_in[0];
  const float* hx = (const float*)d_in[1];
  const int* p_mask = (const int*)d_in[2];
  const int* h_mask = (const int*)d_in[3];
  float* out = (float*)d_out;

  const size_t NE = (size_t)NB * NN * NN;          // 8.4M elements
  const size_t NU = (size_t)NB * 4 * 16 * 512;     // uint4 units per array
  float* E = (float*)d_ws;                         // 33.5 MB fp32
  uint4* pxh = (uint4*)(E + NE);                   // 4 x 16.8 MB tiled bf16
  uint4* pxl = pxh + NU;
  uint4* hxh = pxl + NU;
  uint4* hxl = hxh + NU;
  float* rpm = (float*)(hxl + NU);                 // [B][4][NN] partials
  float* rps = rpm + (size_t)NB * 4 * NN;
  float* cpm = rps + (size_t)NB * 4 * NN;
  float* cps = cpm + (size_t)NB * 4 * NN;
  float* rmaxv = cps + (size_t)NB * 4 * NN;        // [B][NN] finals
  float* rinvv = rmaxv + (size_t)NB * NN;
  float* cmaxv = rinvv + (size_t)NB * NN;
  float* cinvv = cmaxv + (size_t)NB * NN;

  dim3 gg(4, 4, NB);
  convert_tiled<<<dim3(128, 2), dim3(256), 0, stream>>>(px, hx, pxh, pxl, hxh, hxl);
  gemm_e_stats<<<dim3(512), dim3(256), 0, stream>>>(pxh, pxl, hxh, hxl, p_mask, h_mask,
                                                    E, rpm, rps, cpm, cps);
  merge_stats<<<dim3(NB, 2), dim3(512), 0, stream>>>(rpm, rps, cpm, cps,
                                                     rmaxv, rinvv, cmaxv, cinvv);
  gemm_wp<<<gg, dim3(256), 0, stream>>>(E, hx, px, h_mask, rmaxv, rinvv, out);
  gemm_wh<<<gg, dim3(256), 0, stream>>>(E, px, hx, p_mask, cmaxv, cinvv,
                                        out + (size_t)NB * NN * ROWC);
}